// Round 1
// baseline (2234.717 us; speedup 1.0000x reference)
//
#include <hip/hip_runtime.h>
#include <hip/hip_bf16.h>

typedef __attribute__((ext_vector_type(8))) short short8v;
typedef __attribute__((ext_vector_type(4))) float f32x4;
typedef __hip_bfloat16 bf16;

#define BDIM 512
#define NHEADS 8
#define DK 64
#define NBATCH 256
#define NN3 256
#define NN4 64
#define NMLP 2048

// ---------------- weight convert: Wt[n][k] = bf16(W[k][n]) ----------------
__global__ __launch_bounds__(256) void convert_wt_kernel(
    const float* __restrict__ W, bf16* __restrict__ Wt, int K, int N) {
  int idx = blockIdx.x * 256 + threadIdx.x;
  if (idx >= K * N) return;
  int n = idx / K;
  int k = idx - n * K;
  Wt[idx] = __float2bfloat16(W[(size_t)k * N + n]);
}

// ---------------- LayerNorm over 512, optional +pos, optional raw out ------
__global__ __launch_bounds__(256) void ln_kernel(
    const float* __restrict__ x, const float* __restrict__ g,
    const float* __restrict__ beta, const float* __restrict__ pos, int nmod,
    bf16* __restrict__ out1, bf16* __restrict__ out2) {
  int row = blockIdx.x;
  int t = threadIdx.x;
  const float* xr = x + (size_t)row * BDIM;
  float2 v = *(const float2*)(xr + t * 2);
  float s = v.x + v.y;
  float sq = v.x * v.x + v.y * v.y;
  for (int o = 32; o > 0; o >>= 1) {
    s += __shfl_down(s, o);
    sq += __shfl_down(sq, o);
  }
  __shared__ float ls[4], lq[4];
  int w = t >> 6;
  if ((t & 63) == 0) { ls[w] = s; lq[w] = sq; }
  __syncthreads();
  s = ls[0] + ls[1] + ls[2] + ls[3];
  sq = lq[0] + lq[1] + lq[2] + lq[3];
  float mean = s * (1.f / BDIM);
  float var = sq * (1.f / BDIM) - mean * mean;
  float rstd = rsqrtf(var + 1e-5f);
  int n = row % nmod;
  for (int i = 0; i < 2; i++) {
    int c = t * 2 + i;
    float xv = i ? v.y : v.x;
    float nv = (xv - mean) * rstd * g[c] + beta[c];
    if (out2) out2[(size_t)row * BDIM + c] = __float2bfloat16(nv);
    float o1 = nv + (pos ? pos[(size_t)n * BDIM + c] : 0.f);
    out1[(size_t)row * BDIM + c] = __float2bfloat16(o1);
  }
}

// ---------------- generic MFMA GEMM: out[M,N] = X[M,K] @ Wt[N,K]^T --------
// EPI 0: bf16 out = acc + bias
// EPI 1: bf16 out = gelu(acc + bias)
// EPI 2: f32  out = src + acc + bias   (src may alias out)
template <int EPI>
__global__ __launch_bounds__(256) void gemm_kernel(
    const bf16* __restrict__ X, const bf16* __restrict__ Wt,
    const float* __restrict__ bias, const float* src, void* outp,
    int K, int ldx, int ldw, int N) {
  int t = threadIdx.x, w = t >> 6, lane = t & 63;
  int wr = w >> 1, wc = w & 1;
  int row0 = blockIdx.y * 128 + wr * 64;
  int col0 = blockIdx.x * 128 + wc * 64;
  int r16 = lane & 15, kg = lane >> 4;
  f32x4 acc[4][4] = {};
  for (int kt = 0; kt < K / 32; kt++) {
    int kb = kt * 32 + kg * 8;
    short8v a[4], b[4];
#pragma unroll
    for (int mi = 0; mi < 4; mi++)
      a[mi] = *(const short8v*)(X + (size_t)(row0 + mi * 16 + r16) * ldx + kb);
#pragma unroll
    for (int ni = 0; ni < 4; ni++)
      b[ni] = *(const short8v*)(Wt + (size_t)(col0 + ni * 16 + r16) * ldw + kb);
#pragma unroll
    for (int mi = 0; mi < 4; mi++)
#pragma unroll
      for (int ni = 0; ni < 4; ni++)
        acc[mi][ni] =
            __builtin_amdgcn_mfma_f32_16x16x32_bf16(a[mi], b[ni], acc[mi][ni], 0, 0, 0);
  }
#pragma unroll
  for (int ni = 0; ni < 4; ni++) {
    int col = col0 + ni * 16 + r16;
    float bv = bias ? bias[col] : 0.f;
#pragma unroll
    for (int mi = 0; mi < 4; mi++)
#pragma unroll
      for (int r = 0; r < 4; r++) {
        int row = row0 + mi * 16 + kg * 4 + r;
        size_t o = (size_t)row * N + col;
        float val = acc[mi][ni][r] + bv;
        if (EPI == 0) {
          ((bf16*)outp)[o] = __float2bfloat16(val);
        } else if (EPI == 1) {
          float gl = 0.5f * val * (1.f + erff(val * 0.70710678f));
          ((bf16*)outp)[o] = __float2bfloat16(gl);
        } else {
          ((float*)outp)[o] = src[o] + val;
        }
      }
  }
}

// ---------------- softmax over contiguous 64-channel chunks (q) -----------
__global__ __launch_bounds__(256) void qsoftmax_kernel(bf16* q, int nchunks) {
  int wid = (blockIdx.x * 256 + threadIdx.x) >> 6;
  int lane = threadIdx.x & 63;
  if (wid >= nchunks) return;
  float v = __bfloat162float(q[(size_t)wid * 64 + lane]);
  float m = v;
  for (int o = 32; o > 0; o >>= 1) m = fmaxf(m, __shfl_xor(m, o));
  float e = __expf(v - m);
  float s = e;
  for (int o = 32; o > 0; o >>= 1) s += __shfl_xor(s, o);
  q[(size_t)wid * 64 + lane] = __float2bfloat16(e / s);
}

// ---------------- softmax over N4=64 positions per (b, channel) (k) -------
__global__ __launch_bounds__(256) void ksoftmax_kernel(bf16* kbuf) {
  int b = blockIdx.x >> 1;
  int ch = (blockIdx.x & 1) * 256 + threadIdx.x;
  size_t base = (size_t)b * NN4 * BDIM + ch;
  float v[NN4];
  float m = -1e30f;
#pragma unroll
  for (int n = 0; n < NN4; n++) {
    v[n] = __bfloat162float(kbuf[base + (size_t)n * BDIM]);
    m = fmaxf(m, v[n]);
  }
  float s = 0.f;
#pragma unroll
  for (int n = 0; n < NN4; n++) {
    v[n] = __expf(v[n] - m);
    s += v[n];
  }
  float inv = 1.f / s;
#pragma unroll
  for (int n = 0; n < NN4; n++)
    kbuf[base + (size_t)n * BDIM] = __float2bfloat16(v[n] * inv);
}

// ---------------- ctxT[bh][vc][kc] = sum_n V[b,n,h*64+vc] * Ksm[b,n,h*64+kc]
__global__ __launch_bounds__(256) void ctx_kernel(
    const bf16* __restrict__ ksm, const bf16* __restrict__ vbuf,
    bf16* __restrict__ ctxT) {
  int bh = blockIdx.x;
  int b = bh >> 3, h = bh & 7;
  __shared__ bf16 lk[NN4][DK], lv[NN4][DK];
  int t = threadIdx.x;
#pragma unroll
  for (int i = 0; i < 16; i++) {
    int idx = i * 256 + t;
    int n = idx >> 6, c = idx & 63;
    size_t gaddr = (size_t)b * NN4 * BDIM + (size_t)n * BDIM + h * DK + c;
    lk[n][c] = ksm[gaddr];
    lv[n][c] = vbuf[gaddr];
  }
  __syncthreads();
  int vc = t >> 2;
  int kc0 = (t & 3) * 16;
  float acc[16] = {};
  for (int n = 0; n < NN4; n++) {
    float vv = __bfloat162float(lv[n][vc]);
#pragma unroll
    for (int i = 0; i < 16; i++)
      acc[i] += vv * __bfloat162float(lk[n][kc0 + i]);
  }
  size_t o = (size_t)bh * 4096 + (size_t)vc * 64 + kc0;
#pragma unroll
  for (int i = 0; i < 16; i++) ctxT[o + i] = __float2bfloat16(acc[i]);
}

// ---------------- att[b,n,h*64+vc] = sum_kc qsm[b,n,h*64+kc]*ctxT[vc][kc] --
__global__ __launch_bounds__(256) void att_kernel(
    const bf16* __restrict__ qsm, const bf16* __restrict__ ctxT,
    bf16* __restrict__ att) {
  int bh = blockIdx.x;
  int b = bh >> 3, h = bh & 7;
  int t = threadIdx.x, w = t >> 6, lane = t & 63;
  int r16 = lane & 15, kg = lane >> 4;
  f32x4 acc[4][4] = {};
  const bf16* qb = qsm + (size_t)b * NN3 * BDIM + h * DK;
  const bf16* cb = ctxT + (size_t)bh * 4096;
#pragma unroll
  for (int kt = 0; kt < 2; kt++) {
    int kb = kt * 32 + kg * 8;
    short8v a[4], bb[4];
#pragma unroll
    for (int mi = 0; mi < 4; mi++) {
      int rrow = w * 64 + mi * 16 + r16;
      a[mi] = *(const short8v*)(qb + (size_t)rrow * BDIM + kb);
    }
#pragma unroll
    for (int ni = 0; ni < 4; ni++) {
      int vc = ni * 16 + r16;
      bb[ni] = *(const short8v*)(cb + vc * 64 + kb);
    }
#pragma unroll
    for (int mi = 0; mi < 4; mi++)
#pragma unroll
      for (int ni = 0; ni < 4; ni++)
        acc[mi][ni] =
            __builtin_amdgcn_mfma_f32_16x16x32_bf16(a[mi], bb[ni], acc[mi][ni], 0, 0, 0);
  }
#pragma unroll
  for (int mi = 0; mi < 4; mi++)
#pragma unroll
    for (int ni = 0; ni < 4; ni++)
#pragma unroll
      for (int r = 0; r < 4; r++) {
        int row = w * 64 + mi * 16 + kg * 4 + r;
        int col = ni * 16 + r16;
        att[(size_t)(b * NN3 + row) * BDIM + h * DK + col] =
            __float2bfloat16(acc[mi][ni][r]);
      }
}

extern "C" void kernel_launch(void* const* d_in, const int* in_sizes, int n_in,
                              void* d_out, int out_size, void* d_ws, size_t ws_size,
                              hipStream_t stream) {
  const float* f3 = (const float*)d_in[0];
  const float* f4 = (const float*)d_in[1];
  const float* pos3 = (const float*)d_in[2];
  const float* pos4 = (const float*)d_in[3];
  const float* ln1_g = (const float*)d_in[4];
  const float* ln1_b = (const float*)d_in[5];
  const float* ln2_g = (const float*)d_in[6];
  const float* ln2_b = (const float*)d_in[7];
  const float* ln3_g = (const float*)d_in[8];
  const float* ln3_b = (const float*)d_in[9];
  const float* Wq = (const float*)d_in[10];
  const float* bq = (const float*)d_in[11];
  const float* Wk = (const float*)d_in[12];
  const float* bk = (const float*)d_in[13];
  const float* Wv = (const float*)d_in[14];
  const float* bv = (const float*)d_in[15];
  const float* Wr = (const float*)d_in[16];
  const float* br = (const float*)d_in[17];
  const float* W1 = (const float*)d_in[18];
  const float* b1 = (const float*)d_in[19];
  const float* W2 = (const float*)d_in[20];
  const float* b2 = (const float*)d_in[21];
  float* out = (float*)d_out;

  const int M3 = NBATCH * NN3;  // 65536
  const int M4 = NBATCH * NN4;  // 16384

  // ---- workspace layout (bytes) ----
  char* ws = (char*)d_ws;
  size_t off = 0;
  auto alloc = [&](size_t bytes) {
    size_t r = off;
    off = (off + bytes + 255) & ~(size_t)255;
    return r;
  };
  size_t oWqt = alloc((size_t)BDIM * BDIM * 2);
  size_t oWkt = alloc((size_t)BDIM * BDIM * 2);
  size_t oWvt = alloc((size_t)BDIM * BDIM * 2);
  size_t oWrt = alloc((size_t)BDIM * BDIM * 2);
  size_t oW1t = alloc((size_t)BDIM * NMLP * 2);
  size_t oW2t = alloc((size_t)BDIM * NMLP * 2);
  size_t oXQ = alloc((size_t)M3 * BDIM * 2);  // ln(f3)+pos3; reused as att
  size_t oXK = alloc((size_t)M4 * BDIM * 2);  // ln(f4)+pos4
  size_t oXV = alloc((size_t)M4 * BDIM * 2);  // ln(f4)
  size_t oQF = alloc((size_t)M3 * BDIM * 2);  // q proj / q softmax; reused as y (ln3)
  size_t oKF = alloc((size_t)M4 * BDIM * 2);
  size_t oVF = alloc((size_t)M4 * BDIM * 2);
  size_t oCT = alloc((size_t)NBATCH * NHEADS * DK * DK * 2);
  size_t oH1 = alloc((size_t)M3 * 512 * 2);  // MLP chunk (2048/4)
  (void)ws_size;

  bf16* Wqt = (bf16*)(ws + oWqt);
  bf16* Wkt = (bf16*)(ws + oWkt);
  bf16* Wvt = (bf16*)(ws + oWvt);
  bf16* Wrt = (bf16*)(ws + oWrt);
  bf16* W1t = (bf16*)(ws + oW1t);
  bf16* W2t = (bf16*)(ws + oW2t);
  bf16* XQ = (bf16*)(ws + oXQ);
  bf16* XK = (bf16*)(ws + oXK);
  bf16* XV = (bf16*)(ws + oXV);
  bf16* QF = (bf16*)(ws + oQF);
  bf16* KF = (bf16*)(ws + oKF);
  bf16* VF = (bf16*)(ws + oVF);
  bf16* CT = (bf16*)(ws + oCT);
  bf16* H1 = (bf16*)(ws + oH1);
  bf16* ATT = XQ;  // reuse (XQ dead after q projection)
  bf16* Y = QF;    // reuse (QF dead after att)

  // ---- weight conversion ----
  convert_wt_kernel<<<(BDIM * BDIM + 255) / 256, 256, 0, stream>>>(Wq, Wqt, BDIM, BDIM);
  convert_wt_kernel<<<(BDIM * BDIM + 255) / 256, 256, 0, stream>>>(Wk, Wkt, BDIM, BDIM);
  convert_wt_kernel<<<(BDIM * BDIM + 255) / 256, 256, 0, stream>>>(Wv, Wvt, BDIM, BDIM);
  convert_wt_kernel<<<(BDIM * BDIM + 255) / 256, 256, 0, stream>>>(Wr, Wrt, BDIM, BDIM);
  convert_wt_kernel<<<(BDIM * NMLP + 255) / 256, 256, 0, stream>>>(W1, W1t, BDIM, NMLP);
  convert_wt_kernel<<<(BDIM * NMLP + 255) / 256, 256, 0, stream>>>(W2, W2t, NMLP, BDIM);

  // ---- layernorms ----
  ln_kernel<<<M3, 256, 0, stream>>>(f3, ln1_g, ln1_b, pos3, NN3, XQ, nullptr);
  ln_kernel<<<M4, 256, 0, stream>>>(f4, ln2_g, ln2_b, pos4, NN4, XK, XV);

  // ---- projections ----
  gemm_kernel<0><<<dim3(BDIM / 128, M3 / 128), 256, 0, stream>>>(
      XQ, Wqt, bq, nullptr, QF, BDIM, BDIM, BDIM, BDIM);
  gemm_kernel<0><<<dim3(BDIM / 128, M4 / 128), 256, 0, stream>>>(
      XK, Wkt, bk, nullptr, KF, BDIM, BDIM, BDIM, BDIM);
  gemm_kernel<0><<<dim3(BDIM / 128, M4 / 128), 256, 0, stream>>>(
      XV, Wvt, bv, nullptr, VF, BDIM, BDIM, BDIM, BDIM);

  // ---- softmaxes ----
  int nchunks = M3 * NHEADS;  // 524288
  qsoftmax_kernel<<<nchunks / 4, 256, 0, stream>>>(QF, nchunks);
  ksoftmax_kernel<<<NBATCH * 2, 256, 0, stream>>>(KF);

  // ---- context + att ----
  ctx_kernel<<<NBATCH * NHEADS, 256, 0, stream>>>(KF, VF, CT);
  att_kernel<<<NBATCH * NHEADS, 256, 0, stream>>>(QF, CT, ATT);

  // ---- output projection: d_out = f3 + att @ Wr + br (f32) ----
  gemm_kernel<2><<<dim3(BDIM / 128, M3 / 128), 256, 0, stream>>>(
      ATT, Wrt, br, f3, out, BDIM, BDIM, BDIM, BDIM);

  // ---- ln3 on f3o (in d_out) -> Y ----
  ln_kernel<<<M3, 256, 0, stream>>>(out, ln3_g, ln3_b, nullptr, 1, Y, nullptr);

  // ---- MLP, chunked over MLP dim (4 chunks of 512) ----
  for (int c = 0; c < 4; c++) {
    const bf16* W1c = W1t + (size_t)c * 512 * BDIM;  // rows of W1t [2048][512]
    const float* b1c = b1 + c * 512;
    gemm_kernel<1><<<dim3(512 / 128, M3 / 128), 256, 0, stream>>>(
        Y, W1c, b1c, nullptr, H1, BDIM, BDIM, BDIM, 512);
    const bf16* W2c = W2t + (size_t)c * 512;  // col-offset in W2t [512][2048]
    gemm_kernel<2><<<dim3(BDIM / 128, M3 / 128), 256, 0, stream>>>(
        H1, W2c, c == 0 ? b2 : nullptr, out, out, 512, 512, NMLP, BDIM);
  }
}

// Round 4
// 1130.067 us; speedup vs baseline: 1.9775x; 1.9775x over previous
//
#include <hip/hip_runtime.h>
#include <hip/hip_bf16.h>

typedef __attribute__((ext_vector_type(8))) short short8v;
typedef __attribute__((ext_vector_type(4))) float f32x4;
typedef __hip_bfloat16 bf16;

#define BDIM 512
#define NHEADS 8
#define DK 64
#define NBATCH 256
#define NN3 256
#define NN4 64
#define NMLP 2048

#define GLOAD_LDS16(g, l)                                                  \
  __builtin_amdgcn_global_load_lds(                                        \
      (const __attribute__((address_space(1))) void*)(g),                  \
      (__attribute__((address_space(3))) void*)(l), 16, 0, 0)

__device__ __forceinline__ float bf2f(short s) {
  union { short u[2]; float f; } cv;
  cv.u[0] = 0; cv.u[1] = s;
  return cv.f;
}
__device__ __forceinline__ short f2bf(float x) {
  bf16 h = __float2bfloat16(x);
  return *reinterpret_cast<short*>(&h);
}

// ---------------- weight convert: Wt[n][k] = bf16(W[k][n]) ----------------
__global__ __launch_bounds__(256) void convert_wt_kernel(
    const float* __restrict__ W, bf16* __restrict__ Wt, int K, int N) {
  int idx = blockIdx.x * 256 + threadIdx.x;
  if (idx >= K * N) return;
  int n = idx / K;
  int k = idx - n * K;
  Wt[idx] = __float2bfloat16(W[(size_t)k * N + n]);
}

// ---------------- LayerNorm over 512, optional +pos, optional raw out ------
__global__ __launch_bounds__(256) void ln_kernel(
    const float* __restrict__ x, const float* __restrict__ g,
    const float* __restrict__ beta, const float* __restrict__ pos, int nmod,
    bf16* __restrict__ out1, bf16* __restrict__ out2) {
  int row = blockIdx.x;
  int t = threadIdx.x;
  const float* xr = x + (size_t)row * BDIM;
  float2 v = *(const float2*)(xr + t * 2);
  float s = v.x + v.y;
  float sq = v.x * v.x + v.y * v.y;
  for (int o = 32; o > 0; o >>= 1) {
    s += __shfl_down(s, o);
    sq += __shfl_down(sq, o);
  }
  __shared__ float ls[4], lq[4];
  int w = t >> 6;
  if ((t & 63) == 0) { ls[w] = s; lq[w] = sq; }
  __syncthreads();
  s = ls[0] + ls[1] + ls[2] + ls[3];
  sq = lq[0] + lq[1] + lq[2] + lq[3];
  float mean = s * (1.f / BDIM);
  float var = sq * (1.f / BDIM) - mean * mean;
  float rstd = rsqrtf(var + 1e-5f);
  int n = row % nmod;
  for (int i = 0; i < 2; i++) {
    int c = t * 2 + i;
    float xv = i ? v.y : v.x;
    float nv = (xv - mean) * rstd * g[c] + beta[c];
    if (out2) out2[(size_t)row * BDIM + c] = __float2bfloat16(nv);
    float o1 = nv + (pos ? pos[(size_t)n * BDIM + c] : 0.f);
    out1[(size_t)row * BDIM + c] = __float2bfloat16(o1);
  }
}

// ---------------- LDS-staged MFMA GEMM: out[M,N] = X[M,K] @ Wt[N,K]^T -----
// 128x128 tile, BK=64, global_load_lds(16B), XOR-swizzled LDS, XCD swizzle.
// EPI 0: bf16 out = acc + bias
// EPI 1: bf16 out = gelu(acc + bias)
// EPI 2: f32  out = src + acc + bias   (src may alias out)
template <int EPI>
__global__ __launch_bounds__(256) void gemm_kernel(
    const bf16* __restrict__ X, const bf16* __restrict__ Wt,
    const float* __restrict__ bias, const float* __restrict__ src, void* outp,
    int K, int ldx, int ldw, int N, int gridX) {
  __shared__ __align__(128) bf16 lds[16384];  // A [128][64] + B [128][64]

  // XCD-aware bijective swizzle (nwg % 8 == 0 for all our launches)
  int nwg = gridDim.x;
  int cpx = nwg >> 3;
  int bid = blockIdx.x;
  int nb = (bid & 7) * cpx + (bid >> 3);
  int bx = nb % gridX, by = nb / gridX;
  int row0 = by * 128, col0 = bx * 128;

  int t = threadIdx.x, w = t >> 6, lane = t & 63;
  int wr = w >> 1, wc = w & 1;
  int r16 = lane & 15, kg = lane >> 4;

  // staging addresses: wave w stages rows [w*32, w*32+32) of A and of B.
  // LDS is linear; global source column is inverse-swizzled so that
  // LDS byte (r*128 + c) holds global byte (c ^ ((r&7)<<4)) of row r.
  int srow = (lane >> 3);                       // 0..7 within 8-row group
  int scol = ((lane & 7) ^ srow) * 8;           // element offset (swizzled)
  const bf16* gA0 = X + (size_t)(row0 + w * 32 + srow) * ldx + scol;
  const bf16* gB0 = Wt + (size_t)(col0 + w * 32 + srow) * ldw + scol;
  bf16* lA = lds + w * 32 * 64;
  bf16* lB = lds + 8192 + w * 32 * 64;

  f32x4 acc[4][4] = {};
  const char* ldsb = (const char*)lds;

  for (int kt = 0; kt < K; kt += 64) {
#pragma unroll
    for (int j = 0; j < 4; j++)
      GLOAD_LDS16(gA0 + kt + (size_t)j * 8 * ldx, lA + j * 512);
#pragma unroll
    for (int j = 0; j < 4; j++)
      GLOAD_LDS16(gB0 + kt + (size_t)j * 8 * ldw, lB + j * 512);
    __syncthreads();
#pragma unroll
    for (int ksub = 0; ksub < 2; ksub++) {
      int cc = (ksub * 64 + kg * 16) ^ ((r16 & 7) << 4);
      short8v a[4], b[4];
#pragma unroll
      for (int mi = 0; mi < 4; mi++)
        a[mi] = *(const short8v*)(ldsb + (wr * 64 + mi * 16 + r16) * 128 + cc);
#pragma unroll
      for (int ni = 0; ni < 4; ni++)
        b[ni] = *(const short8v*)(ldsb + 16384 + (wc * 64 + ni * 16 + r16) * 128 + cc);
#pragma unroll
      for (int mi = 0; mi < 4; mi++)
#pragma unroll
        for (int ni = 0; ni < 4; ni++)
          acc[mi][ni] =
              __builtin_amdgcn_mfma_f32_16x16x32_bf16(a[mi], b[ni], acc[mi][ni], 0, 0, 0);
    }
    __syncthreads();
  }

#pragma unroll
  for (int ni = 0; ni < 4; ni++) {
    int col = col0 + wc * 64 + ni * 16 + r16;
    float bv = bias ? bias[col] : 0.f;
#pragma unroll
    for (int mi = 0; mi < 4; mi++)
#pragma unroll
      for (int r = 0; r < 4; r++) {
        int row = row0 + wr * 64 + mi * 16 + kg * 4 + r;
        size_t o = (size_t)row * N + col;
        float val = acc[mi][ni][r] + bv;
        if (EPI == 0) {
          ((bf16*)outp)[o] = __float2bfloat16(val);
        } else if (EPI == 1) {
          float gl = 0.5f * val * (1.f + erff(val * 0.70710678f));
          ((bf16*)outp)[o] = __float2bfloat16(gl);
        } else {
          ((float*)outp)[o] = src[o] + val;
        }
      }
  }
}

// ---- ctx: fused k-softmax (over positions) + ctxT[bh][vc][kc] einsum -----
__global__ __launch_bounds__(256) void ctx_kernel(
    const bf16* __restrict__ kproj, const bf16* __restrict__ vbuf,
    bf16* __restrict__ ctxT) {
  int bh = blockIdx.x;
  int b = bh >> 3, h = bh & 7;
  __shared__ bf16 lk[NN4][DK], lv[NN4][DK];
  int t = threadIdx.x;
#pragma unroll
  for (int i = 0; i < 16; i++) {
    int idx = i * 256 + t;
    int n = idx >> 6, c = idx & 63;
    size_t gaddr = (size_t)b * NN4 * BDIM + (size_t)n * BDIM + h * DK + c;
    lk[n][c] = kproj[gaddr];
    lv[n][c] = vbuf[gaddr];
  }
  __syncthreads();
  // k-softmax over n (64 positions) per channel c; threads 0..63 active
  if (t < 64) {
    int c = t;
    float e[NN4];
    float m = -1e30f;
#pragma unroll
    for (int n = 0; n < NN4; n++) {
      e[n] = bf2f(*(short*)&lk[n][c]);
      m = fmaxf(m, e[n]);
    }
    float s = 0.f;
#pragma unroll
    for (int n = 0; n < NN4; n++) {
      e[n] = __expf(e[n] - m);
      s += e[n];
    }
    float inv = 1.f / s;
#pragma unroll
    for (int n = 0; n < NN4; n++) lk[n][c] = __float2bfloat16(e[n] * inv);
  }
  __syncthreads();
  int vc = t >> 2;
  int kc0 = (t & 3) * 16;
  float acc[16] = {};
  for (int n = 0; n < NN4; n++) {
    float vv = __bfloat162float(lv[n][vc]);
#pragma unroll
    for (int i = 0; i < 16; i++)
      acc[i] += vv * __bfloat162float(lk[n][kc0 + i]);
  }
  size_t o = (size_t)bh * 4096 + (size_t)vc * 64 + kc0;
#pragma unroll
  for (int i = 0; i < 16; i++) ctxT[o + i] = __float2bfloat16(acc[i]);
}

// ---- att: fused q-softmax (in-register, over 64 head channels) + GEMM ----
__global__ __launch_bounds__(256) void att_kernel(
    const bf16* __restrict__ qproj, const bf16* __restrict__ ctxT,
    bf16* __restrict__ att) {
  int bh = blockIdx.x;
  int b = bh >> 3, h = bh & 7;
  int t = threadIdx.x, w = t >> 6, lane = t & 63;
  int r16 = lane & 15, kg = lane >> 4;
  f32x4 acc[4][4] = {};
  const bf16* qb = qproj + (size_t)b * NN3 * BDIM + h * DK;
  const bf16* cb = ctxT + (size_t)bh * 4096;
  short8v bb[2][4];
#pragma unroll
  for (int kt = 0; kt < 2; kt++)
#pragma unroll
    for (int ni = 0; ni < 4; ni++)
      bb[kt][ni] = *(const short8v*)(cb + (ni * 16 + r16) * 64 + kt * 32 + kg * 8);
#pragma unroll
  for (int mi = 0; mi < 4; mi++) {
    int rrow = w * 64 + mi * 16 + r16;
    short8v a0 = *(const short8v*)(qb + (size_t)rrow * BDIM + kg * 8);
    short8v a1 = *(const short8v*)(qb + (size_t)rrow * BDIM + 32 + kg * 8);
    // softmax over this row's 64 channels: 16 in-lane + lanes across kg
    float f[16];
#pragma unroll
    for (int i = 0; i < 8; i++) {
      f[i] = bf2f(a0[i]);
      f[8 + i] = bf2f(a1[i]);
    }
    float m = f[0];
#pragma unroll
    for (int i = 1; i < 16; i++) m = fmaxf(m, f[i]);
    m = fmaxf(m, __shfl_xor(m, 16));
    m = fmaxf(m, __shfl_xor(m, 32));
    float s = 0.f;
#pragma unroll
    for (int i = 0; i < 16; i++) {
      f[i] = __expf(f[i] - m);
      s += f[i];
    }
    s += __shfl_xor(s, 16);
    s += __shfl_xor(s, 32);
    float inv = 1.f / s;
    short8v A0, A1;
#pragma unroll
    for (int i = 0; i < 8; i++) {
      A0[i] = f2bf(f[i] * inv);
      A1[i] = f2bf(f[8 + i] * inv);
    }
#pragma unroll
    for (int ni = 0; ni < 4; ni++) {
      acc[mi][ni] = __builtin_amdgcn_mfma_f32_16x16x32_bf16(A0, bb[0][ni], acc[mi][ni], 0, 0, 0);
      acc[mi][ni] = __builtin_amdgcn_mfma_f32_16x16x32_bf16(A1, bb[1][ni], acc[mi][ni], 0, 0, 0);
    }
  }
#pragma unroll
  for (int mi = 0; mi < 4; mi++)
#pragma unroll
    for (int ni = 0; ni < 4; ni++)
#pragma unroll
      for (int r = 0; r < 4; r++) {
        int row = w * 64 + mi * 16 + kg * 4 + r;
        int col = ni * 16 + r16;
        att[(size_t)(b * NN3 + row) * BDIM + h * DK + col] =
            __float2bfloat16(acc[mi][ni][r]);
      }
}

extern "C" void kernel_launch(void* const* d_in, const int* in_sizes, int n_in,
                              void* d_out, int out_size, void* d_ws, size_t ws_size,
                              hipStream_t stream) {
  const float* f3 = (const float*)d_in[0];
  const float* f4 = (const float*)d_in[1];
  const float* pos3 = (const float*)d_in[2];
  const float* pos4 = (const float*)d_in[3];
  const float* ln1_g = (const float*)d_in[4];
  const float* ln1_b = (const float*)d_in[5];
  const float* ln2_g = (const float*)d_in[6];
  const float* ln2_b = (const float*)d_in[7];
  const float* ln3_g = (const float*)d_in[8];
  const float* ln3_b = (const float*)d_in[9];
  const float* Wq = (const float*)d_in[10];
  const float* bq = (const float*)d_in[11];
  const float* Wk = (const float*)d_in[12];
  const float* bk = (const float*)d_in[13];
  const float* Wv = (const float*)d_in[14];
  const float* bv = (const float*)d_in[15];
  const float* Wr = (const float*)d_in[16];
  const float* br = (const float*)d_in[17];
  const float* W1 = (const float*)d_in[18];
  const float* b1 = (const float*)d_in[19];
  const float* W2 = (const float*)d_in[20];
  const float* b2 = (const float*)d_in[21];
  float* out = (float*)d_out;

  const int M3 = NBATCH * NN3;  // 65536
  const int M4 = NBATCH * NN4;  // 16384
  const int MC = M3 / 4;        // 16384 MLP row-chunk

  char* ws = (char*)d_ws;
  size_t off = 0;
  auto alloc = [&](size_t bytes) {
    size_t r = off;
    off = (off + bytes + 255) & ~(size_t)255;
    return r;
  };
  size_t oWqt = alloc((size_t)BDIM * BDIM * 2);
  size_t oWkt = alloc((size_t)BDIM * BDIM * 2);
  size_t oWvt = alloc((size_t)BDIM * BDIM * 2);
  size_t oWrt = alloc((size_t)BDIM * BDIM * 2);
  size_t oW1t = alloc((size_t)BDIM * NMLP * 2);
  size_t oW2t = alloc((size_t)BDIM * NMLP * 2);
  size_t oXQ = alloc((size_t)M3 * BDIM * 2);  // ln(f3)+pos3; reused as att
  size_t oXK = alloc((size_t)M4 * BDIM * 2);  // ln(f4)+pos4
  size_t oXV = alloc((size_t)M4 * BDIM * 2);  // ln(f4)
  size_t oQF = alloc((size_t)M3 * BDIM * 2);  // raw q proj; reused as y (ln3)
  size_t oKF = alloc((size_t)M4 * BDIM * 2);
  size_t oVF = alloc((size_t)M4 * BDIM * 2);
  size_t oCT = alloc((size_t)NBATCH * NHEADS * DK * DK * 2);
  size_t oH1 = alloc((size_t)MC * NMLP * 2);  // MLP hidden row-chunk
  (void)ws_size;

  bf16* Wqt = (bf16*)(ws + oWqt);
  bf16* Wkt = (bf16*)(ws + oWkt);
  bf16* Wvt = (bf16*)(ws + oWvt);
  bf16* Wrt = (bf16*)(ws + oWrt);
  bf16* W1t = (bf16*)(ws + oW1t);
  bf16* W2t = (bf16*)(ws + oW2t);
  bf16* XQ = (bf16*)(ws + oXQ);
  bf16* XK = (bf16*)(ws + oXK);
  bf16* XV = (bf16*)(ws + oXV);
  bf16* QF = (bf16*)(ws + oQF);
  bf16* KF = (bf16*)(ws + oKF);
  bf16* VF = (bf16*)(ws + oVF);
  bf16* CT = (bf16*)(ws + oCT);
  bf16* H1 = (bf16*)(ws + oH1);
  bf16* ATT = XQ;  // reuse (XQ dead after q projection)
  bf16* Y = QF;    // reuse (QF dead after att)

  // ---- weight conversion ----
  convert_wt_kernel<<<(BDIM * BDIM + 255) / 256, 256, 0, stream>>>(Wq, Wqt, BDIM, BDIM);
  convert_wt_kernel<<<(BDIM * BDIM + 255) / 256, 256, 0, stream>>>(Wk, Wkt, BDIM, BDIM);
  convert_wt_kernel<<<(BDIM * BDIM + 255) / 256, 256, 0, stream>>>(Wv, Wvt, BDIM, BDIM);
  convert_wt_kernel<<<(BDIM * BDIM + 255) / 256, 256, 0, stream>>>(Wr, Wrt, BDIM, BDIM);
  convert_wt_kernel<<<(BDIM * NMLP + 255) / 256, 256, 0, stream>>>(W1, W1t, BDIM, NMLP);
  convert_wt_kernel<<<(BDIM * NMLP + 255) / 256, 256, 0, stream>>>(W2, W2t, NMLP, BDIM);

  // ---- layernorms ----
  ln_kernel<<<M3, 256, 0, stream>>>(f3, ln1_g, ln1_b, pos3, NN3, XQ, nullptr);
  ln_kernel<<<M4, 256, 0, stream>>>(f4, ln2_g, ln2_b, pos4, NN4, XK, XV);

  // ---- projections (q raw; softmaxes fused downstream) ----
  gemm_kernel<0><<<(BDIM / 128) * (M3 / 128), 256, 0, stream>>>(
      XQ, Wqt, bq, nullptr, QF, BDIM, BDIM, BDIM, BDIM, BDIM / 128);
  gemm_kernel<0><<<(BDIM / 128) * (M4 / 128), 256, 0, stream>>>(
      XK, Wkt, bk, nullptr, KF, BDIM, BDIM, BDIM, BDIM, BDIM / 128);
  gemm_kernel<0><<<(BDIM / 128) * (M4 / 128), 256, 0, stream>>>(
      XV, Wvt, bv, nullptr, VF, BDIM, BDIM, BDIM, BDIM, BDIM / 128);

  // ---- context (fused k-softmax) + att (fused q-softmax) ----
  ctx_kernel<<<NBATCH * NHEADS, 256, 0, stream>>>(KF, VF, CT);
  att_kernel<<<NBATCH * NHEADS, 256, 0, stream>>>(QF, CT, ATT);

  // ---- output projection: d_out = f3 + att @ Wr + br (f32) ----
  gemm_kernel<2><<<(BDIM / 128) * (M3 / 128), 256, 0, stream>>>(
      ATT, Wrt, br, f3, out, BDIM, BDIM, BDIM, BDIM, BDIM / 128);

  // ---- ln3 on f3o (in d_out) -> Y ----
  ln_kernel<<<M3, 256, 0, stream>>>(out, ln3_g, ln3_b, nullptr, 1, Y, nullptr);

  // ---- MLP, chunked over rows (4 chunks of 16384) ----
  for (int c = 0; c < 4; c++) {
    const bf16* Yc = Y + (size_t)c * MC * BDIM;
    float* outc = out + (size_t)c * MC * BDIM;
    gemm_kernel<1><<<(NMLP / 128) * (MC / 128), 256, 0, stream>>>(
        Yc, W1t, b1, nullptr, H1, BDIM, BDIM, BDIM, NMLP, NMLP / 128);
    gemm_kernel<2><<<(BDIM / 128) * (MC / 128), 256, 0, stream>>>(
        H1, W2t, b2, outc, outc, NMLP, NMLP, NMLP, BDIM, BDIM / 128);
  }
}

// Round 5
// 1101.194 us; speedup vs baseline: 2.0294x; 1.0262x over previous
//
#include <hip/hip_runtime.h>
#include <hip/hip_bf16.h>

typedef __attribute__((ext_vector_type(8))) short short8v;
typedef __attribute__((ext_vector_type(4))) float f32x4;
typedef __hip_bfloat16 bf16;

#define BDIM 512
#define NHEADS 8
#define DK 64
#define NBATCH 256
#define NN3 256
#define NN4 64
#define NMLP 2048

#define GLOAD_LDS16(g, l)                                                  \
  __builtin_amdgcn_global_load_lds(                                        \
      (const __attribute__((address_space(1))) void*)(g),                  \
      (__attribute__((address_space(3))) void*)(l), 16, 0, 0)

__device__ __forceinline__ float bf2f(short s) {
  union { short u[2]; float f; } cv;
  cv.u[0] = 0; cv.u[1] = s;
  return cv.f;
}
__device__ __forceinline__ short f2bf(float x) {
  bf16 h = __float2bfloat16(x);
  return *reinterpret_cast<short*>(&h);
}

// ---------------- weight convert: Wt[n][k] = bf16(W[k][n]) ----------------
__global__ __launch_bounds__(256) void convert_wt_kernel(
    const float* __restrict__ W, bf16* __restrict__ Wt, int K, int N) {
  int idx = blockIdx.x * 256 + threadIdx.x;
  if (idx >= K * N) return;
  int n = idx / K;
  int k = idx - n * K;
  Wt[idx] = __float2bfloat16(W[(size_t)k * N + n]);
}

// ---------------- LayerNorm over 512, optional +pos, optional raw out ------
__global__ __launch_bounds__(256) void ln_kernel(
    const float* __restrict__ x, const float* __restrict__ g,
    const float* __restrict__ beta, const float* __restrict__ pos, int nmod,
    bf16* __restrict__ out1, bf16* __restrict__ out2) {
  int row = blockIdx.x;
  int t = threadIdx.x;
  const float* xr = x + (size_t)row * BDIM;
  float2 v = *(const float2*)(xr + t * 2);
  float s = v.x + v.y;
  float sq = v.x * v.x + v.y * v.y;
  for (int o = 32; o > 0; o >>= 1) {
    s += __shfl_down(s, o);
    sq += __shfl_down(sq, o);
  }
  __shared__ float ls[4], lq[4];
  int w = t >> 6;
  if ((t & 63) == 0) { ls[w] = s; lq[w] = sq; }
  __syncthreads();
  s = ls[0] + ls[1] + ls[2] + ls[3];
  sq = lq[0] + lq[1] + lq[2] + lq[3];
  float mean = s * (1.f / BDIM);
  float var = sq * (1.f / BDIM) - mean * mean;
  float rstd = rsqrtf(var + 1e-5f);
  int n = row % nmod;
  for (int i = 0; i < 2; i++) {
    int c = t * 2 + i;
    float xv = i ? v.y : v.x;
    float nv = (xv - mean) * rstd * g[c] + beta[c];
    if (out2) out2[(size_t)row * BDIM + c] = __float2bfloat16(nv);
    float o1 = nv + (pos ? pos[(size_t)n * BDIM + c] : 0.f);
    out1[(size_t)row * BDIM + c] = __float2bfloat16(o1);
  }
}

// ---------------- LDS-staged MFMA GEMM: out[M,N] = X[M,K] @ Wt[N,K]^T -----
// 128x128 tile, BK=64, DOUBLE-BUFFERED prefetch (stage t+1 before compute t),
// global_load_lds(16B), XOR-swizzled LDS, XCD swizzle.
// EPI 0: bf16 out = acc + bias
// EPI 1: bf16 out = gelu(acc + bias)
// EPI 2: f32  out = src + acc + bias   (src may alias out)
template <int EPI>
__global__ __launch_bounds__(256) void gemm_kernel(
    const bf16* __restrict__ X, const bf16* __restrict__ Wt,
    const float* __restrict__ bias, const float* __restrict__ src, void* outp,
    int K, int ldx, int ldw, int N, int gridX) {
  // 2 buffers x (A [128][64] + B [128][64]) bf16 = 65536 bytes
  __shared__ __align__(128) bf16 lds[32768];

  // XCD-aware bijective swizzle (nwg % 8 == 0 for all our launches)
  int nwg = gridDim.x;
  int cpx = nwg >> 3;
  int bid = blockIdx.x;
  int nb = (bid & 7) * cpx + (bid >> 3);
  int bx = nb % gridX, by = nb / gridX;
  int row0 = by * 128, col0 = bx * 128;

  int t = threadIdx.x, w = t >> 6, lane = t & 63;
  int wr = w >> 1, wc = w & 1;
  int r16 = lane & 15, kg = lane >> 4;

  // staging: wave w stages rows [w*32, w*32+32) of A and of B.
  // LDS is linear per buffer; global source column inverse-swizzled so that
  // LDS byte (r*128 + c) holds global byte (c ^ ((r&7)<<4)) of row r.
  int srow = (lane >> 3);                       // 0..7 within 8-row group
  int scol = ((lane & 7) ^ srow) * 8;           // element offset (swizzled)
  const bf16* gA0 = X + (size_t)(row0 + w * 32 + srow) * ldx + scol;
  const bf16* gB0 = Wt + (size_t)(col0 + w * 32 + srow) * ldw + scol;

  f32x4 acc[4][4] = {};

  auto stage = [&](int ktel, int buf) {
    bf16* lA = lds + buf * 16384 + w * 32 * 64;
    bf16* lB = lds + buf * 16384 + 8192 + w * 32 * 64;
#pragma unroll
    for (int j = 0; j < 4; j++) {
      GLOAD_LDS16(gA0 + ktel + (size_t)j * 8 * ldx, lA + j * 512);
      GLOAD_LDS16(gB0 + ktel + (size_t)j * 8 * ldw, lB + j * 512);
    }
  };

  auto compute = [&](int buf) {
    const char* base = (const char*)lds + buf * 32768;
#pragma unroll
    for (int ksub = 0; ksub < 2; ksub++) {
      int cc = (ksub * 64 + kg * 16) ^ ((r16 & 7) << 4);
      short8v a[4], b[4];
#pragma unroll
      for (int mi = 0; mi < 4; mi++)
        a[mi] = *(const short8v*)(base + (wr * 64 + mi * 16 + r16) * 128 + cc);
#pragma unroll
      for (int ni = 0; ni < 4; ni++)
        b[ni] = *(const short8v*)(base + 16384 + (wc * 64 + ni * 16 + r16) * 128 + cc);
#pragma unroll
      for (int mi = 0; mi < 4; mi++)
#pragma unroll
        for (int ni = 0; ni < 4; ni++)
          acc[mi][ni] =
              __builtin_amdgcn_mfma_f32_16x16x32_bf16(a[mi], b[ni], acc[mi][ni], 0, 0, 0);
    }
  };

  int NT = K >> 6;
  stage(0, 0);
  __syncthreads();  // drains vmcnt(0): buf0 ready
  int cur = 0;
  for (int kt = 1; kt < NT; kt++) {
    stage(kt << 6, cur ^ 1);   // prefetch next tile (overlaps compute below)
    compute(cur);
    __syncthreads();           // drains vmcnt(0) + lgkm: next buf ready,
    cur ^= 1;                  // and all waves done reading old buf
  }
  compute(cur);

#pragma unroll
  for (int ni = 0; ni < 4; ni++) {
    int col = col0 + wc * 64 + ni * 16 + r16;
    float bv = bias ? bias[col] : 0.f;
#pragma unroll
    for (int mi = 0; mi < 4; mi++)
#pragma unroll
      for (int r = 0; r < 4; r++) {
        int row = row0 + wr * 64 + mi * 16 + kg * 4 + r;
        size_t o = (size_t)row * N + col;
        float val = acc[mi][ni][r] + bv;
        if (EPI == 0) {
          ((bf16*)outp)[o] = __float2bfloat16(val);
        } else if (EPI == 1) {
          float gl = 0.5f * val * (1.f + erff(val * 0.70710678f));
          ((bf16*)outp)[o] = __float2bfloat16(gl);
        } else {
          ((float*)outp)[o] = src[o] + val;
        }
      }
  }
}

// ---- ctx: fused k-softmax (over positions) + ctxT[bh][vc][kc] einsum -----
__global__ __launch_bounds__(256) void ctx_kernel(
    const bf16* __restrict__ kproj, const bf16* __restrict__ vbuf,
    bf16* __restrict__ ctxT) {
  int bh = blockIdx.x;
  int b = bh >> 3, h = bh & 7;
  __shared__ bf16 lk[NN4][DK], lv[NN4][DK];
  int t = threadIdx.x;
#pragma unroll
  for (int i = 0; i < 16; i++) {
    int idx = i * 256 + t;
    int n = idx >> 6, c = idx & 63;
    size_t gaddr = (size_t)b * NN4 * BDIM + (size_t)n * BDIM + h * DK + c;
    lk[n][c] = kproj[gaddr];
    lv[n][c] = vbuf[gaddr];
  }
  __syncthreads();
  // k-softmax over n (64 positions) per channel c; threads 0..63 active
  if (t < 64) {
    int c = t;
    float e[NN4];
    float m = -1e30f;
#pragma unroll
    for (int n = 0; n < NN4; n++) {
      e[n] = bf2f(*(short*)&lk[n][c]);
      m = fmaxf(m, e[n]);
    }
    float s = 0.f;
#pragma unroll
    for (int n = 0; n < NN4; n++) {
      e[n] = __expf(e[n] - m);
      s += e[n];
    }
    float inv = 1.f / s;
#pragma unroll
    for (int n = 0; n < NN4; n++) lk[n][c] = __float2bfloat16(e[n] * inv);
  }
  __syncthreads();
  int vc = t >> 2;
  int kc0 = (t & 3) * 16;
  float acc[16] = {};
  for (int n = 0; n < NN4; n++) {
    float vv = __bfloat162float(lv[n][vc]);
#pragma unroll
    for (int i = 0; i < 16; i++)
      acc[i] += vv * __bfloat162float(lk[n][kc0 + i]);
  }
  size_t o = (size_t)bh * 4096 + (size_t)vc * 64 + kc0;
#pragma unroll
  for (int i = 0; i < 16; i++) ctxT[o + i] = __float2bfloat16(acc[i]);
}

// ---- att: fused q-softmax (in-register, over 64 head channels) + GEMM ----
__global__ __launch_bounds__(256) void att_kernel(
    const bf16* __restrict__ qproj, const bf16* __restrict__ ctxT,
    bf16* __restrict__ att) {
  int bh = blockIdx.x;
  int b = bh >> 3, h = bh & 7;
  int t = threadIdx.x, w = t >> 6, lane = t & 63;
  int r16 = lane & 15, kg = lane >> 4;
  f32x4 acc[4][4] = {};
  const bf16* qb = qproj + (size_t)b * NN3 * BDIM + h * DK;
  const bf16* cb = ctxT + (size_t)bh * 4096;
  short8v bb[2][4];
#pragma unroll
  for (int kt = 0; kt < 2; kt++)
#pragma unroll
    for (int ni = 0; ni < 4; ni++)
      bb[kt][ni] = *(const short8v*)(cb + (ni * 16 + r16) * 64 + kt * 32 + kg * 8);
#pragma unroll
  for (int mi = 0; mi < 4; mi++) {
    int rrow = w * 64 + mi * 16 + r16;
    short8v a0 = *(const short8v*)(qb + (size_t)rrow * BDIM + kg * 8);
    short8v a1 = *(const short8v*)(qb + (size_t)rrow * BDIM + 32 + kg * 8);
    // softmax over this row's 64 channels: 16 in-lane + lanes across kg
    float f[16];
#pragma unroll
    for (int i = 0; i < 8; i++) {
      f[i] = bf2f(a0[i]);
      f[8 + i] = bf2f(a1[i]);
    }
    float m = f[0];
#pragma unroll
    for (int i = 1; i < 16; i++) m = fmaxf(m, f[i]);
    m = fmaxf(m, __shfl_xor(m, 16));
    m = fmaxf(m, __shfl_xor(m, 32));
    float s = 0.f;
#pragma unroll
    for (int i = 0; i < 16; i++) {
      f[i] = __expf(f[i] - m);
      s += f[i];
    }
    s += __shfl_xor(s, 16);
    s += __shfl_xor(s, 32);
    float inv = 1.f / s;
    short8v A0, A1;
#pragma unroll
    for (int i = 0; i < 8; i++) {
      A0[i] = f2bf(f[i] * inv);
      A1[i] = f2bf(f[8 + i] * inv);
    }
#pragma unroll
    for (int ni = 0; ni < 4; ni++) {
      acc[mi][ni] = __builtin_amdgcn_mfma_f32_16x16x32_bf16(A0, bb[0][ni], acc[mi][ni], 0, 0, 0);
      acc[mi][ni] = __builtin_amdgcn_mfma_f32_16x16x32_bf16(A1, bb[1][ni], acc[mi][ni], 0, 0, 0);
    }
  }
#pragma unroll
  for (int mi = 0; mi < 4; mi++)
#pragma unroll
    for (int ni = 0; ni < 4; ni++)
#pragma unroll
      for (int r = 0; r < 4; r++) {
        int row = w * 64 + mi * 16 + kg * 4 + r;
        int col = ni * 16 + r16;
        att[(size_t)(b * NN3 + row) * BDIM + h * DK + col] =
            __float2bfloat16(acc[mi][ni][r]);
      }
}

extern "C" void kernel_launch(void* const* d_in, const int* in_sizes, int n_in,
                              void* d_out, int out_size, void* d_ws, size_t ws_size,
                              hipStream_t stream) {
  const float* f3 = (const float*)d_in[0];
  const float* f4 = (const float*)d_in[1];
  const float* pos3 = (const float*)d_in[2];
  const float* pos4 = (const float*)d_in[3];
  const float* ln1_g = (const float*)d_in[4];
  const float* ln1_b = (const float*)d_in[5];
  const float* ln2_g = (const float*)d_in[6];
  const float* ln2_b = (const float*)d_in[7];
  const float* ln3_g = (const float*)d_in[8];
  const float* ln3_b = (const float*)d_in[9];
  const float* Wq = (const float*)d_in[10];
  const float* bq = (const float*)d_in[11];
  const float* Wk = (const float*)d_in[12];
  const float* bk = (const float*)d_in[13];
  const float* Wv = (const float*)d_in[14];
  const float* bv = (const float*)d_in[15];
  const float* Wr = (const float*)d_in[16];
  const float* br = (const float*)d_in[17];
  const float* W1 = (const float*)d_in[18];
  const float* b1 = (const float*)d_in[19];
  const float* W2 = (const float*)d_in[20];
  const float* b2 = (const float*)d_in[21];
  float* out = (float*)d_out;

  const int M3 = NBATCH * NN3;  // 65536
  const int M4 = NBATCH * NN4;  // 16384
  const int MC = M3 / 4;        // 16384 MLP row-chunk

  char* ws = (char*)d_ws;
  size_t off = 0;
  auto alloc = [&](size_t bytes) {
    size_t r = off;
    off = (off + bytes + 255) & ~(size_t)255;
    return r;
  };
  size_t oWqt = alloc((size_t)BDIM * BDIM * 2);
  size_t oWkt = alloc((size_t)BDIM * BDIM * 2);
  size_t oWvt = alloc((size_t)BDIM * BDIM * 2);
  size_t oWrt = alloc((size_t)BDIM * BDIM * 2);
  size_t oW1t = alloc((size_t)BDIM * NMLP * 2);
  size_t oW2t = alloc((size_t)BDIM * NMLP * 2);
  size_t oXQ = alloc((size_t)M3 * BDIM * 2);  // ln(f3)+pos3; reused as att
  size_t oXK = alloc((size_t)M4 * BDIM * 2);  // ln(f4)+pos4
  size_t oXV = alloc((size_t)M4 * BDIM * 2);  // ln(f4)
  size_t oQF = alloc((size_t)M3 * BDIM * 2);  // raw q proj; reused as y (ln3)
  size_t oKF = alloc((size_t)M4 * BDIM * 2);
  size_t oVF = alloc((size_t)M4 * BDIM * 2);
  size_t oCT = alloc((size_t)NBATCH * NHEADS * DK * DK * 2);
  size_t oH1 = alloc((size_t)MC * NMLP * 2);  // MLP hidden row-chunk
  (void)ws_size;

  bf16* Wqt = (bf16*)(ws + oWqt);
  bf16* Wkt = (bf16*)(ws + oWkt);
  bf16* Wvt = (bf16*)(ws + oWvt);
  bf16* Wrt = (bf16*)(ws + oWrt);
  bf16* W1t = (bf16*)(ws + oW1t);
  bf16* W2t = (bf16*)(ws + oW2t);
  bf16* XQ = (bf16*)(ws + oXQ);
  bf16* XK = (bf16*)(ws + oXK);
  bf16* XV = (bf16*)(ws + oXV);
  bf16* QF = (bf16*)(ws + oQF);
  bf16* KF = (bf16*)(ws + oKF);
  bf16* VF = (bf16*)(ws + oVF);
  bf16* CT = (bf16*)(ws + oCT);
  bf16* H1 = (bf16*)(ws + oH1);
  bf16* ATT = XQ;  // reuse (XQ dead after q projection)
  bf16* Y = QF;    // reuse (QF dead after att)

  // ---- weight conversion ----
  convert_wt_kernel<<<(BDIM * BDIM + 255) / 256, 256, 0, stream>>>(Wq, Wqt, BDIM, BDIM);
  convert_wt_kernel<<<(BDIM * BDIM + 255) / 256, 256, 0, stream>>>(Wk, Wkt, BDIM, BDIM);
  convert_wt_kernel<<<(BDIM * BDIM + 255) / 256, 256, 0, stream>>>(Wv, Wvt, BDIM, BDIM);
  convert_wt_kernel<<<(BDIM * BDIM + 255) / 256, 256, 0, stream>>>(Wr, Wrt, BDIM, BDIM);
  convert_wt_kernel<<<(BDIM * NMLP + 255) / 256, 256, 0, stream>>>(W1, W1t, BDIM, NMLP);
  convert_wt_kernel<<<(BDIM * NMLP + 255) / 256, 256, 0, stream>>>(W2, W2t, NMLP, BDIM);

  // ---- layernorms ----
  ln_kernel<<<M3, 256, 0, stream>>>(f3, ln1_g, ln1_b, pos3, NN3, XQ, nullptr);
  ln_kernel<<<M4, 256, 0, stream>>>(f4, ln2_g, ln2_b, pos4, NN4, XK, XV);

  // ---- projections (q raw; softmaxes fused downstream) ----
  gemm_kernel<0><<<(BDIM / 128) * (M3 / 128), 256, 0, stream>>>(
      XQ, Wqt, bq, nullptr, QF, BDIM, BDIM, BDIM, BDIM, BDIM / 128);
  gemm_kernel<0><<<(BDIM / 128) * (M4 / 128), 256, 0, stream>>>(
      XK, Wkt, bk, nullptr, KF, BDIM, BDIM, BDIM, BDIM, BDIM / 128);
  gemm_kernel<0><<<(BDIM / 128) * (M4 / 128), 256, 0, stream>>>(
      XV, Wvt, bv, nullptr, VF, BDIM, BDIM, BDIM, BDIM, BDIM / 128);

  // ---- context (fused k-softmax) + att (fused q-softmax) ----
  ctx_kernel<<<NBATCH * NHEADS, 256, 0, stream>>>(KF, VF, CT);
  att_kernel<<<NBATCH * NHEADS, 256, 0, stream>>>(QF, CT, ATT);

  // ---- output projection: d_out = f3 + att @ Wr + br (f32) ----
  gemm_kernel<2><<<(BDIM / 128) * (M3 / 128), 256, 0, stream>>>(
      ATT, Wrt, br, f3, out, BDIM, BDIM, BDIM, BDIM, BDIM / 128);

  // ---- ln3 on f3o (in d_out) -> Y ----
  ln_kernel<<<M3, 256, 0, stream>>>(out, ln3_g, ln3_b, nullptr, 1, Y, nullptr);

  // ---- MLP, chunked over rows (4 chunks of 16384) ----
  for (int c = 0; c < 4; c++) {
    const bf16* Yc = Y + (size_t)c * MC * BDIM;
    float* outc = out + (size_t)c * MC * BDIM;
    gemm_kernel<1><<<(NMLP / 128) * (MC / 128), 256, 0, stream>>>(
        Yc, W1t, b1, nullptr, H1, BDIM, BDIM, BDIM, NMLP, NMLP / 128);
    gemm_kernel<2><<<(BDIM / 128) * (MC / 128), 256, 0, stream>>>(
        H1, W2t, b2, outc, outc, NMLP, NMLP, NMLP, BDIM, BDIM / 128);
  }
}